// Round 1
// baseline (502.948 us; speedup 1.0000x reference)
//
#include <hip/hip_runtime.h>

// Problem constants (reference: H=16, T=2048, D=1024, DH=64)
#define TT 2048
#define DD 1024
#define HH 16
#define DH 64
#define QKV_N 3072

// ---------------------------------------------------------------------------
// Kernel 1: inclusive cumsum of done -> seg[t]; total -> totalp[0]
// ---------------------------------------------------------------------------
__global__ __launch_bounds__(256) void scan_kernel(const int* __restrict__ done,
                                                   int* __restrict__ seg,
                                                   int* __restrict__ totalp) {
    __shared__ int part[256];
    __shared__ int excl[256];
    int tid = threadIdx.x;
    int base = tid * 8;
    int local[8];
    int run = 0;
#pragma unroll
    for (int i = 0; i < 8; ++i) {
        run += (done[base + i] != 0) ? 1 : 0;
        local[i] = run;
    }
    part[tid] = run;
    __syncthreads();
    if (tid == 0) {
        int r = 0;
        for (int i = 0; i < 256; ++i) { excl[i] = r; r += part[i]; }
        totalp[0] = r;
    }
    __syncthreads();
    int off = excl[tid];
#pragma unroll
    for (int i = 0; i < 8; ++i) seg[base + i] = off + local[i];
}

// ---------------------------------------------------------------------------
// Kernel 2: generic fp32 GEMM with bias: C[M,N] = A[M,K] @ B[K,N] + bias[N]
// 64x64 tile, 16x16 threads, 4x4 per thread, BK=16.
// ---------------------------------------------------------------------------
#define GT 64
#define GBK 16
#define GPAD 68

__global__ __launch_bounds__(256) void gemm_bias(const float* __restrict__ A,
                                                 const float* __restrict__ B,
                                                 const float* __restrict__ bias,
                                                 float* __restrict__ C,
                                                 int M, int N, int K) {
    __shared__ float As[GBK][GPAD];  // As[k][m]  (A tile transposed)
    __shared__ float Bs[GBK][GPAD];  // Bs[k][n]
    int tid = threadIdx.x;
    int tx = tid & 15, ty = tid >> 4;
    int m0 = blockIdx.x * GT, n0 = blockIdx.y * GT;
    float acc[4][4] = {};

    for (int k0 = 0; k0 < K; k0 += GBK) {
        {   // A tile: 64 rows x 16 k, transposed store
            int r = tid >> 2;
            int kq = (tid & 3) * 4;
            float4 a = *(const float4*)&A[(size_t)(m0 + r) * K + k0 + kq];
            As[kq + 0][r] = a.x; As[kq + 1][r] = a.y;
            As[kq + 2][r] = a.z; As[kq + 3][r] = a.w;
        }
        {   // B tile: 16 rows(k) x 64 n, natural store
            int kr = tid >> 4;
            int nc = (tid & 15) * 4;
            *(float4*)&Bs[kr][nc] = *(const float4*)&B[(size_t)(k0 + kr) * N + n0 + nc];
        }
        __syncthreads();
#pragma unroll
        for (int kk = 0; kk < GBK; ++kk) {
            float4 a4 = *(const float4*)&As[kk][ty * 4];
            float4 b4 = *(const float4*)&Bs[kk][tx * 4];
            float a[4] = {a4.x, a4.y, a4.z, a4.w};
            float b[4] = {b4.x, b4.y, b4.z, b4.w};
#pragma unroll
            for (int i = 0; i < 4; ++i)
#pragma unroll
                for (int j = 0; j < 4; ++j) acc[i][j] += a[i] * b[j];
        }
        __syncthreads();
    }
#pragma unroll
    for (int i = 0; i < 4; ++i) {
        int col = n0 + tx * 4;
        float4 c;
        c.x = acc[i][0] + bias[col + 0];
        c.y = acc[i][1] + bias[col + 1];
        c.z = acc[i][2] + bias[col + 2];
        c.w = acc[i][3] + bias[col + 3];
        *(float4*)&C[(size_t)(m0 + ty * 4 + i) * N + col] = c;
    }
}

// ---------------------------------------------------------------------------
// Kernel 3: attention. Block = (head h, t-tile tt of 64 rows).
// out[t,e] = sum_{s same seg, s<=t} (q_t . k_s) v_s[e]  + [seg[t]==0] * (q_t @ state_h)
// Written to outb[(t)*D + h*64 + e].
// ---------------------------------------------------------------------------
__global__ __launch_bounds__(256) void attn_kernel(const float* __restrict__ qkv,
                                                   const float* __restrict__ state,
                                                   const int* __restrict__ seg,
                                                   float* __restrict__ outb) {
    __shared__ float Qt[64][GPAD];  // Qt[d][t]
    __shared__ float KB[64][GPAD];  // K^T [d][s]; reused as state [d][e] and S^T [s][t]
    __shared__ float Vs[64][GPAD];  // Vs[s][e]
    __shared__ int segT[64];
    __shared__ int segS[64];

    int h = blockIdx.x;
    int tt = blockIdx.y;
    int tid = threadIdx.x, tx = tid & 15, ty = tid >> 4;
    int t0 = tt * 64;

    // Load Q tile transposed + state tile natural
#pragma unroll
    for (int rep = 0; rep < 4; ++rep) {
        int r = rep * 16 + ty;
        int dg = tx * 4;
        float4 qv = *(const float4*)&qkv[(size_t)(t0 + r) * QKV_N + h * DH + dg];
        Qt[dg + 0][r] = qv.x; Qt[dg + 1][r] = qv.y;
        Qt[dg + 2][r] = qv.z; Qt[dg + 3][r] = qv.w;
        *(float4*)&KB[r][dg] = *(const float4*)&state[(size_t)h * DH * DH + r * DH + dg];
    }
    if (tid < 64) segT[tid] = seg[t0 + tid];
    __syncthreads();

    float acc[4][4] = {};
    // state gemm: acc[t][e] = sum_d Q[t][d] * state[d][e]
#pragma unroll 8
    for (int kk = 0; kk < 64; ++kk) {
        float4 a4 = *(const float4*)&Qt[kk][ty * 4];
        float4 b4 = *(const float4*)&KB[kk][tx * 4];
        float a[4] = {a4.x, a4.y, a4.z, a4.w};
        float b[4] = {b4.x, b4.y, b4.z, b4.w};
#pragma unroll
        for (int i = 0; i < 4; ++i)
#pragma unroll
            for (int j = 0; j < 4; ++j) acc[i][j] += a[i] * b[j];
    }
    // mask: only rows with seg==0 (before first reset) keep state contribution
#pragma unroll
    for (int i = 0; i < 4; ++i)
        if (segT[ty * 4 + i] != 0)
#pragma unroll
            for (int j = 0; j < 4; ++j) acc[i][j] = 0.f;

    int segmin = segT[0];  // seg monotonic -> min over t rows
    __syncthreads();       // state-gemm reads of KB done before s-loop overwrites

    for (int st = 0; st <= tt; ++st) {
        int s0 = st * 64;
        // whole s-tile in an earlier segment than every t row -> fully masked
        if (seg[s0 + 63] < segmin) continue;  // uniform branch

        // Load K tile transposed, V tile natural, segS
#pragma unroll
        for (int rep = 0; rep < 4; ++rep) {
            int r = rep * 16 + ty;
            int dg = tx * 4;
            float4 kv = *(const float4*)&qkv[(size_t)(s0 + r) * QKV_N + DD + h * DH + dg];
            KB[dg + 0][r] = kv.x; KB[dg + 1][r] = kv.y;
            KB[dg + 2][r] = kv.z; KB[dg + 3][r] = kv.w;
            *(float4*)&Vs[r][dg] = *(const float4*)&qkv[(size_t)(s0 + r) * QKV_N + 2 * DD + h * DH + dg];
        }
        if (tid < 64) segS[tid] = seg[s0 + tid];
        __syncthreads();

        // S = Q @ K^T  (t rows x s cols)
        float sacc[4][4] = {};
#pragma unroll 8
        for (int kk = 0; kk < 64; ++kk) {
            float4 a4 = *(const float4*)&Qt[kk][ty * 4];
            float4 b4 = *(const float4*)&KB[kk][tx * 4];
            float a[4] = {a4.x, a4.y, a4.z, a4.w};
            float b[4] = {b4.x, b4.y, b4.z, b4.w};
#pragma unroll
            for (int i = 0; i < 4; ++i)
#pragma unroll
                for (int j = 0; j < 4; ++j) sacc[i][j] += a[i] * b[j];
        }
        __syncthreads();  // all reads of KB done; safe to overwrite with S^T

        // masked store S^T into KB: KB[s][t]
#pragma unroll
        for (int i = 0; i < 4; ++i) {
            int tl = ty * 4 + i;
#pragma unroll
            for (int j = 0; j < 4; ++j) {
                int sl = tx * 4 + j;
                bool ok = (segS[sl] == segT[tl]) && (s0 + sl <= t0 + tl);
                KB[sl][tl] = ok ? sacc[i][j] : 0.f;
            }
        }
        __syncthreads();

        // out += S @ V
#pragma unroll 8
        for (int kk = 0; kk < 64; ++kk) {
            float4 a4 = *(const float4*)&KB[kk][ty * 4];
            float4 b4 = *(const float4*)&Vs[kk][tx * 4];
            float a[4] = {a4.x, a4.y, a4.z, a4.w};
            float b[4] = {b4.x, b4.y, b4.z, b4.w};
#pragma unroll
            for (int i = 0; i < 4; ++i)
#pragma unroll
                for (int j = 0; j < 4; ++j) acc[i][j] += a[i] * b[j];
        }
        __syncthreads();
    }

    // epilogue: outb[t, h*64+e]
#pragma unroll
    for (int i = 0; i < 4; ++i) {
        float4 c = make_float4(acc[i][0], acc[i][1], acc[i][2], acc[i][3]);
        *(float4*)&outb[(size_t)(t0 + ty * 4 + i) * DD + h * DH + tx * 4] = c;
    }
}

// ---------------------------------------------------------------------------
// Kernel 4: new_state[h] = (done_any ? 0 : state[h]) + sum_{t: seg[t]==total} k_t^T v_t
// ---------------------------------------------------------------------------
__global__ __launch_bounds__(256) void state_kernel(const float* __restrict__ qkv,
                                                    const float* __restrict__ state,
                                                    const int* __restrict__ seg,
                                                    const int* __restrict__ totalp,
                                                    float* __restrict__ out) {
    __shared__ float Ks[64][GPAD];
    __shared__ float Vs[64][GPAD];
    __shared__ int segc[64];
    int h = blockIdx.x;
    int tid = threadIdx.x, tx = tid & 15, ty = tid >> 4;
    int total = totalp[0];
    bool done_any = total > 0;

    float acc[4][4];
#pragma unroll
    for (int i = 0; i < 4; ++i)
#pragma unroll
        for (int j = 0; j < 4; ++j)
            acc[i][j] = done_any ? 0.f
                                 : state[(size_t)h * DH * DH + (ty * 4 + i) * DH + tx * 4 + j];

    for (int ct = 0; ct < 32; ++ct) {
        int t0 = ct * 64;
        if (seg[t0 + 63] < total) continue;  // uniform: no seg==total in chunk

#pragma unroll
        for (int rep = 0; rep < 4; ++rep) {
            int r = rep * 16 + ty;
            int dg = tx * 4;
            *(float4*)&Ks[r][dg] = *(const float4*)&qkv[(size_t)(t0 + r) * QKV_N + DD + h * DH + dg];
            *(float4*)&Vs[r][dg] = *(const float4*)&qkv[(size_t)(t0 + r) * QKV_N + 2 * DD + h * DH + dg];
        }
        if (tid < 64) segc[tid] = seg[t0 + tid];
        __syncthreads();

        for (int u = 0; u < 64; ++u) {
            if (segc[u] == total) {  // uniform branch
                float4 a4 = *(const float4*)&Ks[u][ty * 4];
                float4 b4 = *(const float4*)&Vs[u][tx * 4];
                float a[4] = {a4.x, a4.y, a4.z, a4.w};
                float b[4] = {b4.x, b4.y, b4.z, b4.w};
#pragma unroll
                for (int i = 0; i < 4; ++i)
#pragma unroll
                    for (int j = 0; j < 4; ++j) acc[i][j] += a[i] * b[j];
            }
        }
        __syncthreads();
    }

#pragma unroll
    for (int i = 0; i < 4; ++i) {
        float4 c = make_float4(acc[i][0], acc[i][1], acc[i][2], acc[i][3]);
        *(float4*)&out[(size_t)h * DH * DH + (ty * 4 + i) * DH + tx * 4] = c;
    }
}

// ---------------------------------------------------------------------------
// Host launcher
// ---------------------------------------------------------------------------
extern "C" void kernel_launch(void* const* d_in, const int* in_sizes, int n_in,
                              void* d_out, int out_size, void* d_ws, size_t ws_size,
                              hipStream_t stream) {
    const float* state = (const float*)d_in[0];   // (H, DH, DH)
    const float* x     = (const float*)d_in[1];   // (T, D)
    const int*   done  = (const int*)d_in[2];     // (T,)
    const float* w_qkv = (const float*)d_in[3];   // (D, 3D)
    const float* b_qkv = (const float*)d_in[4];   // (3D,)
    const float* w_out = (const float*)d_in[5];   // (D, D)
    const float* b_out = (const float*)d_in[6];   // (D,)

    // workspace layout
    int* seg    = (int*)d_ws;                       // 2048 ints
    int* totalp = seg + TT;                         // 1 int (+pad)
    float* qkv  = (float*)((char*)d_ws + 8448);     // T x 3D floats (25.2 MB)
    float* outb = qkv + (size_t)TT * QKV_N;         // T x D floats (8.4 MB)

    float* new_state_out = (float*)d_out;           // 65536 floats
    float* x_out         = (float*)d_out + HH * DH * DH;  // 2097152 floats

    // 1. segment scan
    scan_kernel<<<1, 256, 0, stream>>>(done, seg, totalp);

    // 2. QKV projection: (T x D) @ (D x 3D) + b_qkv
    gemm_bias<<<dim3(TT / GT, QKV_N / GT), 256, 0, stream>>>(x, w_qkv, b_qkv, qkv,
                                                             TT, QKV_N, DD);

    // 3. attention
    attn_kernel<<<dim3(HH, TT / 64), 256, 0, stream>>>(qkv, state, seg, outb);

    // 4. new state
    state_kernel<<<HH, 256, 0, stream>>>(qkv, state, seg, totalp, new_state_out);

    // 5. output projection: (T x D) @ (D x D) + b_out
    gemm_bias<<<dim3(TT / GT, DD / GT), 256, 0, stream>>>(outb, w_out, b_out, x_out,
                                                          TT, DD, DD);
}

// Round 2
// 270.983 us; speedup vs baseline: 1.8560x; 1.8560x over previous
//
#include <hip/hip_runtime.h>

#define TT 2048
#define DD 1024
#define HH 16
#define DH 64
#define QKV_N 3072

typedef __attribute__((ext_vector_type(8))) short bf16x8;
typedef __attribute__((ext_vector_type(4))) float f32x4;

__device__ inline short f2bf(float f) {
    union { float f; unsigned u; } v; v.f = f;
    unsigned r = v.u + 0x7fff + ((v.u >> 16) & 1);  // RNE
    return (short)(r >> 16);
}
__device__ inline float bflo(unsigned u) { union { unsigned x; float f; } v; v.x = u << 16; return v.f; }
__device__ inline float bfhi(unsigned u) { union { unsigned x; float f; } v; v.x = u & 0xffff0000u; return v.f; }

__device__ inline f32x4 mfma16(bf16x8 a, bf16x8 b, f32x4 c) {
    return __builtin_amdgcn_mfma_f32_16x16x32_bf16(a, b, c, 0, 0, 0);
}

// ---------------------------------------------------------------------------
// 1. inclusive cumsum of done
// ---------------------------------------------------------------------------
__global__ __launch_bounds__(256) void scan_kernel(const int* __restrict__ done,
                                                   int* __restrict__ seg,
                                                   int* __restrict__ totalp) {
    __shared__ int part[256];
    __shared__ int excl[256];
    int tid = threadIdx.x;
    int base = tid * 8;
    int local[8];
    int run = 0;
#pragma unroll
    for (int i = 0; i < 8; ++i) { run += (done[base + i] != 0) ? 1 : 0; local[i] = run; }
    part[tid] = run;
    __syncthreads();
    if (tid == 0) {
        int r = 0;
        for (int i = 0; i < 256; ++i) { excl[i] = r; r += part[i]; }
        totalp[0] = r;
    }
    __syncthreads();
    int off = excl[tid];
#pragma unroll
    for (int i = 0; i < 8; ++i) seg[base + i] = off + local[i];
}

// ---------------------------------------------------------------------------
// 2. casts
// ---------------------------------------------------------------------------
__global__ __launch_bounds__(256) void cast_bf16(const float* __restrict__ in,
                                                 short* __restrict__ out, int n) {
    int i = (blockIdx.x * 256 + threadIdx.x) * 8;
    if (i >= n) return;
    float4 a = *(const float4*)&in[i];
    float4 b = *(const float4*)&in[i + 4];
    short tmp[8] = {f2bf(a.x), f2bf(a.y), f2bf(a.z), f2bf(a.w),
                    f2bf(b.x), f2bf(b.y), f2bf(b.z), f2bf(b.w)};
    *(float4*)&out[i] = *(float4*)tmp;
}

// in[b][R][C] fp32 -> out[b][C][R] bf16, R,C multiples of 64
__global__ __launch_bounds__(256) void transpose_cast(const float* __restrict__ in,
                                                      short* __restrict__ out,
                                                      int R, int C) {
    __shared__ float tile[64][65];
    int r0 = blockIdx.x * 64, c0 = blockIdx.y * 64;
    size_t boff = (size_t)blockIdx.z * R * C;
    int tid = threadIdx.x;
#pragma unroll
    for (int p = 0; p < 4; ++p) {
        int ch = tid + p * 256;          // 0..1023
        int r = ch >> 4, c4 = (ch & 15) * 4;
        float4 v = *(const float4*)&in[boff + (size_t)(r0 + r) * C + c0 + c4];
        tile[r][c4] = v.x; tile[r][c4 + 1] = v.y; tile[r][c4 + 2] = v.z; tile[r][c4 + 3] = v.w;
    }
    __syncthreads();
#pragma unroll
    for (int p = 0; p < 2; ++p) {
        int ch = tid + p * 256;          // 0..511
        int c = ch >> 3, r8 = (ch & 7) * 8;
        short tmp[8];
#pragma unroll
        for (int i = 0; i < 8; ++i) tmp[i] = f2bf(tile[r8 + i][c]);
        *(float4*)&out[boff + (size_t)(c0 + c) * R + r0 + r8] = *(float4*)tmp;
    }
}

// ---------------------------------------------------------------------------
// 3. bf16 MFMA GEMM, B^T input: C[M,N] = A[M,K] @ BT[N,K]^T + bias
// 128x128 tile, BK=32, 4 waves, 4x4 16x16x32 MFMA per wave.
// ---------------------------------------------------------------------------
#define ASTR 40  // padded LDS row stride (elems): 2-way conflicts only (free)

template <bool BF16OUT>
__global__ __launch_bounds__(256) void gemm_bt(const short* __restrict__ A,
                                               const short* __restrict__ BT,
                                               const float* __restrict__ bias,
                                               void* __restrict__ Cout,
                                               int M, int N, int K) {
    __shared__ short As[128 * ASTR];
    __shared__ short Bs[128 * ASTR];
    int tid = threadIdx.x;
    int wave = tid >> 6, lane = tid & 63;
    int quad = lane >> 4, l15 = lane & 15;
    int m0 = blockIdx.x * 128, n0 = blockIdx.y * 128;
    int wr = (wave >> 1) * 64, wc = (wave & 1) * 64;

    f32x4 acc[4][4] = {};
    for (int k0 = 0; k0 < K; k0 += 32) {
        __syncthreads();
#pragma unroll
        for (int p = 0; p < 2; ++p) {
            int idx = tid + p * 256;     // 0..511
            int r = idx >> 2, c8 = (idx & 3) * 8;
            *(float4*)&As[r * ASTR + c8] = *(const float4*)&A[(size_t)(m0 + r) * K + k0 + c8];
            *(float4*)&Bs[r * ASTR + c8] = *(const float4*)&BT[(size_t)(n0 + r) * K + k0 + c8];
        }
        __syncthreads();
        bf16x8 af[4], bfr[4];
#pragma unroll
        for (int i = 0; i < 4; ++i) {
            af[i]  = *(const bf16x8*)&As[(wr + i * 16 + l15) * ASTR + quad * 8];
            bfr[i] = *(const bf16x8*)&Bs[(wc + i * 16 + l15) * ASTR + quad * 8];
        }
#pragma unroll
        for (int i = 0; i < 4; ++i)
#pragma unroll
            for (int j = 0; j < 4; ++j)
                acc[i][j] = mfma16(af[i], bfr[j], acc[i][j]);
    }
#pragma unroll
    for (int i = 0; i < 4; ++i)
#pragma unroll
        for (int j = 0; j < 4; ++j)
#pragma unroll
            for (int r = 0; r < 4; ++r) {
                int row = m0 + wr + i * 16 + quad * 4 + r;
                int col = n0 + wc + j * 16 + l15;
                float v = acc[i][j][r] + bias[col];
                if (BF16OUT) ((short*)Cout)[(size_t)row * N + col] = f2bf(v);
                else        ((float*)Cout)[(size_t)row * N + col] = v;
            }
}

// ---------------------------------------------------------------------------
// 4. attention with MFMA. block=(h, t-tile of 64), 4 waves (one 16-row strip each)
// ---------------------------------------------------------------------------
#define SQ 72  // LDS row stride (elems); 144B rows -> 2-way frag conflicts (free)

__global__ __launch_bounds__(256) void attn_mfma(const short* __restrict__ qkv,
                                                 const short* __restrict__ stateT,
                                                 const int* __restrict__ seg,
                                                 short* __restrict__ outb) {
    __shared__ short Qs[64 * SQ];
    __shared__ short Ks[64 * SQ];  // stateT first, then K tiles
    __shared__ short Vt[64 * SQ];  // V transposed [e][s]
    __shared__ short Ss[64 * SQ];  // masked S [t][s]
    __shared__ int segT[64], segS[64];

    int h = blockIdx.x, tt = blockIdx.y;
    int t0 = tt * 64;
    int tid = threadIdx.x, wave = tid >> 6, lane = tid & 63;
    int quad = lane >> 4, l15 = lane & 15;
    int myt = wave * 16;

    // stage Q tile (natural) + stateT tile
#pragma unroll
    for (int p = 0; p < 2; ++p) {
        int idx = tid + p * 256;         // 0..511
        int r = idx >> 3, c8 = (idx & 7) * 8;
        *(float4*)&Qs[r * SQ + c8] = *(const float4*)&qkv[(size_t)(t0 + r) * QKV_N + h * DH + c8];
        *(float4*)&Ks[r * SQ + c8] = *(const float4*)&stateT[(size_t)h * 4096 + r * 64 + c8];
    }
    if (tid < 64) segT[tid] = seg[t0 + tid];
    __syncthreads();

    bf16x8 qf[2];
    qf[0] = *(const bf16x8*)&Qs[(myt + l15) * SQ + quad * 8];
    qf[1] = *(const bf16x8*)&Qs[(myt + l15) * SQ + 32 + quad * 8];

    f32x4 acc[4] = {};
    // state contribution: Q @ state (B operand = stateT[e][d])
#pragma unroll
    for (int j = 0; j < 4; ++j) {
        bf16x8 b0 = *(const bf16x8*)&Ks[(j * 16 + l15) * SQ + quad * 8];
        bf16x8 b1 = *(const bf16x8*)&Ks[(j * 16 + l15) * SQ + 32 + quad * 8];
        acc[j] = mfma16(qf[0], b0, acc[j]);
        acc[j] = mfma16(qf[1], b1, acc[j]);
    }
#pragma unroll
    for (int r = 0; r < 4; ++r) {
        int t = myt + quad * 4 + r;
        if (segT[t] != 0) { acc[0][r] = 0.f; acc[1][r] = 0.f; acc[2][r] = 0.f; acc[3][r] = 0.f; }
    }
    int seg_t_first = segT[0];

    for (int st = 0; st <= tt; ++st) {
        int s0 = st * 64;
        if (seg[s0 + 63] < seg_t_first) continue;  // block-uniform skip
        __syncthreads();                           // prior reads of Ks/Vt/Ss done
        // stage K (natural [s][d]) and V (transposed [e][s], lane-rotated scatter)
#pragma unroll
        for (int p = 0; p < 2; ++p) {
            int idx = tid + p * 256;
            int r = idx >> 3, c8 = (idx & 7) * 8;
            *(float4*)&Ks[r * SQ + c8] = *(const float4*)&qkv[(size_t)(s0 + r) * QKV_N + DD + h * DH + c8];
            union { float4 f; short s[8]; } uv;
            uv.f = *(const float4*)&qkv[(size_t)(s0 + r) * QKV_N + 2 * DD + h * DH + c8];
#pragma unroll
            for (int ii = 0; ii < 8; ++ii) {
                int i = (ii + lane) & 7;  // rotate to spread banks
                Vt[(c8 + i) * SQ + r] = uv.s[i];
            }
        }
        if (tid < 64) segS[tid] = seg[s0 + tid];
        __syncthreads();

        // S = Q @ K^T (B operand = K[s][d] natural)
        f32x4 sacc[4] = {};
#pragma unroll
        for (int j = 0; j < 4; ++j) {
            bf16x8 b0 = *(const bf16x8*)&Ks[(j * 16 + l15) * SQ + quad * 8];
            bf16x8 b1 = *(const bf16x8*)&Ks[(j * 16 + l15) * SQ + 32 + quad * 8];
            sacc[j] = mfma16(qf[0], b0, sacc[j]);
            sacc[j] = mfma16(qf[1], b1, sacc[j]);
        }
        // masked C-layout -> A-layout round trip through LDS
#pragma unroll
        for (int j = 0; j < 4; ++j)
#pragma unroll
            for (int r = 0; r < 4; ++r) {
                int t = myt + quad * 4 + r;
                int s = j * 16 + l15;
                bool ok = (segS[s] == segT[t]) && (s0 + s <= t0 + t);
                Ss[t * SQ + s] = ok ? f2bf(sacc[j][r]) : (short)0;
            }
        __syncthreads();

        // out += S @ V
        bf16x8 sf0 = *(const bf16x8*)&Ss[(myt + l15) * SQ + quad * 8];
        bf16x8 sf1 = *(const bf16x8*)&Ss[(myt + l15) * SQ + 32 + quad * 8];
#pragma unroll
        for (int j = 0; j < 4; ++j) {
            bf16x8 b0 = *(const bf16x8*)&Vt[(j * 16 + l15) * SQ + quad * 8];
            bf16x8 b1 = *(const bf16x8*)&Vt[(j * 16 + l15) * SQ + 32 + quad * 8];
            acc[j] = mfma16(sf0, b0, acc[j]);
            acc[j] = mfma16(sf1, b1, acc[j]);
        }
    }

    // epilogue: outb[t][h*64+e] bf16
#pragma unroll
    for (int j = 0; j < 4; ++j)
#pragma unroll
        for (int r = 0; r < 4; ++r) {
            int t = t0 + myt + quad * 4 + r;
            int e = j * 16 + l15;
            outb[(size_t)t * DD + h * DH + e] = f2bf(acc[j][r]);
        }
}

// ---------------------------------------------------------------------------
// 5. new_state = (done_any ? 0 : state) + K_aft^T @ V_aft   (fp32 VALU; tiny)
// ---------------------------------------------------------------------------
__global__ __launch_bounds__(256) void state_kernel(const short* __restrict__ qkv,
                                                    const float* __restrict__ state,
                                                    const int* __restrict__ seg,
                                                    const int* __restrict__ totalp,
                                                    float* __restrict__ out) {
    __shared__ float Ks[64][68];
    __shared__ float Vs[64][68];
    __shared__ int segc[64];
    int h = blockIdx.x;
    int tid = threadIdx.x, tx = tid & 15, ty = tid >> 4;
    int total = totalp[0];
    bool done_any = total > 0;

    float acc[4][4];
#pragma unroll
    for (int i = 0; i < 4; ++i)
#pragma unroll
        for (int j = 0; j < 4; ++j)
            acc[i][j] = done_any ? 0.f
                                 : state[(size_t)h * DH * DH + (ty * 4 + i) * DH + tx * 4 + j];

    for (int ct = 0; ct < 32; ++ct) {
        int t0 = ct * 64;
        if (seg[t0 + 63] < total) continue;
#pragma unroll
        for (int p = 0; p < 2; ++p) {
            int idx = tid + p * 256;
            int r = idx >> 3, c8 = (idx & 7) * 8;
            uint4 uk = *(const uint4*)&qkv[(size_t)(t0 + r) * QKV_N + DD + h * DH + c8];
            uint4 uvv = *(const uint4*)&qkv[(size_t)(t0 + r) * QKV_N + 2 * DD + h * DH + c8];
            Ks[r][c8 + 0] = bflo(uk.x); Ks[r][c8 + 1] = bfhi(uk.x);
            Ks[r][c8 + 2] = bflo(uk.y); Ks[r][c8 + 3] = bfhi(uk.y);
            Ks[r][c8 + 4] = bflo(uk.z); Ks[r][c8 + 5] = bfhi(uk.z);
            Ks[r][c8 + 6] = bflo(uk.w); Ks[r][c8 + 7] = bfhi(uk.w);
            Vs[r][c8 + 0] = bflo(uvv.x); Vs[r][c8 + 1] = bfhi(uvv.x);
            Vs[r][c8 + 2] = bflo(uvv.y); Vs[r][c8 + 3] = bfhi(uvv.y);
            Vs[r][c8 + 4] = bflo(uvv.z); Vs[r][c8 + 5] = bfhi(uvv.z);
            Vs[r][c8 + 6] = bflo(uvv.w); Vs[r][c8 + 7] = bfhi(uvv.w);
        }
        if (tid < 64) segc[tid] = seg[t0 + tid];
        __syncthreads();
        for (int u = 0; u < 64; ++u) {
            if (segc[u] == total) {
                float4 a4 = *(const float4*)&Ks[u][ty * 4];
                float4 b4 = *(const float4*)&Vs[u][tx * 4];
                float a[4] = {a4.x, a4.y, a4.z, a4.w};
                float b[4] = {b4.x, b4.y, b4.z, b4.w};
#pragma unroll
                for (int i = 0; i < 4; ++i)
#pragma unroll
                    for (int j = 0; j < 4; ++j) acc[i][j] += a[i] * b[j];
            }
        }
        __syncthreads();
    }
#pragma unroll
    for (int i = 0; i < 4; ++i) {
        float4 c = make_float4(acc[i][0], acc[i][1], acc[i][2], acc[i][3]);
        *(float4*)&out[(size_t)h * DH * DH + (ty * 4 + i) * DH + tx * 4] = c;
    }
}

// ---------------------------------------------------------------------------
// Host launcher
// ---------------------------------------------------------------------------
extern "C" void kernel_launch(void* const* d_in, const int* in_sizes, int n_in,
                              void* d_out, int out_size, void* d_ws, size_t ws_size,
                              hipStream_t stream) {
    const float* state = (const float*)d_in[0];
    const float* x     = (const float*)d_in[1];
    const int*   done  = (const int*)d_in[2];
    const float* w_qkv = (const float*)d_in[3];
    const float* b_qkv = (const float*)d_in[4];
    const float* w_out = (const float*)d_in[5];
    const float* b_out = (const float*)d_in[6];

    char* ws = (char*)d_ws;
    int*   seg    = (int*)ws;                                  // 8 KB
    int*   totalp = (int*)(ws + 8192);
    short* x_bf   = (short*)(ws + 8448);                       // 4 MB
    short* wqT    = (short*)(ws + 8448 + 4194304);             // 6 MB  [3072][1024]
    short* woT    = (short*)(ws + 8448 + 10485760);            // 2 MB  [1024][1024]
    short* stT    = (short*)(ws + 8448 + 12582912);            // 128 KB [h][e][d]
    short* qkvb   = (short*)(ws + 8448 + 12713984);            // 12 MB [T][3072]
    short* outb   = (short*)(ws + 8448 + 25296896);            // 4 MB  [T][1024]

    float* new_state_out = (float*)d_out;
    float* x_out         = (float*)d_out + HH * DH * DH;

    scan_kernel<<<1, 256, 0, stream>>>(done, seg, totalp);
    cast_bf16<<<(TT * DD) / (8 * 256), 256, 0, stream>>>(x, x_bf, TT * DD);
    transpose_cast<<<dim3(DD / 64, QKV_N / 64, 1), 256, 0, stream>>>(w_qkv, wqT, DD, QKV_N);
    transpose_cast<<<dim3(DD / 64, DD / 64, 1), 256, 0, stream>>>(w_out, woT, DD, DD);
    transpose_cast<<<dim3(1, 1, HH), 256, 0, stream>>>(state, stT, DH, DH);

    gemm_bt<true><<<dim3(TT / 128, QKV_N / 128), 256, 0, stream>>>(
        x_bf, wqT, b_qkv, qkvb, TT, QKV_N, DD);

    attn_mfma<<<dim3(HH, TT / 64), 256, 0, stream>>>(qkvb, stT, seg, outb);

    state_kernel<<<HH, 256, 0, stream>>>(qkvb, state, seg, totalp, new_state_out);

    gemm_bt<false><<<dim3(TT / 128, DD / 128), 256, 0, stream>>>(
        outb, woT, b_out, x_out, TT, DD, DD);
}

// Round 3
// 193.067 us; speedup vs baseline: 2.6050x; 1.4036x over previous
//
#include <hip/hip_runtime.h>

#define TT 2048
#define DD 1024
#define HH 16
#define DH 64
#define QKV_N 3072

typedef __attribute__((ext_vector_type(8))) short bf16x8;
typedef __attribute__((ext_vector_type(4))) float f32x4;

__device__ inline short f2bf(float f) {
    union { float f; unsigned u; } v; v.f = f;
    unsigned r = v.u + 0x7fff + ((v.u >> 16) & 1);  // RNE
    return (short)(r >> 16);
}

__device__ inline f32x4 mfma16(bf16x8 a, bf16x8 b, f32x4 c) {
    return __builtin_amdgcn_mfma_f32_16x16x32_bf16(a, b, c, 0, 0, 0);
}

// ---------------------------------------------------------------------------
// 1. inclusive cumsum of done
// ---------------------------------------------------------------------------
__global__ __launch_bounds__(256) void scan_kernel(const int* __restrict__ done,
                                                   int* __restrict__ seg,
                                                   int* __restrict__ totalp) {
    __shared__ int part[256];
    __shared__ int excl[256];
    int tid = threadIdx.x;
    int base = tid * 8;
    int local[8];
    int run = 0;
#pragma unroll
    for (int i = 0; i < 8; ++i) { run += (done[base + i] != 0) ? 1 : 0; local[i] = run; }
    part[tid] = run;
    __syncthreads();
    if (tid == 0) {
        int r = 0;
        for (int i = 0; i < 256; ++i) { excl[i] = r; r += part[i]; }
        totalp[0] = r;
    }
    __syncthreads();
    int off = excl[tid];
#pragma unroll
    for (int i = 0; i < 8; ++i) seg[base + i] = off + local[i];
}

// ---------------------------------------------------------------------------
// 2. casts
// ---------------------------------------------------------------------------
__global__ __launch_bounds__(256) void cast_bf16(const float* __restrict__ in,
                                                 short* __restrict__ out, int n) {
    int i = (blockIdx.x * 256 + threadIdx.x) * 8;
    if (i >= n) return;
    float4 a = *(const float4*)&in[i];
    float4 b = *(const float4*)&in[i + 4];
    short tmp[8] = {f2bf(a.x), f2bf(a.y), f2bf(a.z), f2bf(a.w),
                    f2bf(b.x), f2bf(b.y), f2bf(b.z), f2bf(b.w)};
    *(float4*)&out[i] = *(float4*)tmp;
}

// in[b][R][C] fp32 -> out[b][C][R] bf16, R,C multiples of 64
__global__ __launch_bounds__(256) void transpose_cast(const float* __restrict__ in,
                                                      short* __restrict__ out,
                                                      int R, int C) {
    __shared__ float tile[64][65];
    int r0 = blockIdx.x * 64, c0 = blockIdx.y * 64;
    size_t boff = (size_t)blockIdx.z * R * C;
    int tid = threadIdx.x;
#pragma unroll
    for (int p = 0; p < 4; ++p) {
        int ch = tid + p * 256;
        int r = ch >> 4, c4 = (ch & 15) * 4;
        float4 v = *(const float4*)&in[boff + (size_t)(r0 + r) * C + c0 + c4];
        tile[r][c4] = v.x; tile[r][c4 + 1] = v.y; tile[r][c4 + 2] = v.z; tile[r][c4 + 3] = v.w;
    }
    __syncthreads();
#pragma unroll
    for (int p = 0; p < 2; ++p) {
        int ch = tid + p * 256;
        int c = ch >> 3, r8 = (ch & 7) * 8;
        short tmp[8];
#pragma unroll
        for (int i = 0; i < 8; ++i) tmp[i] = f2bf(tile[r8 + i][c]);
        *(float4*)&out[boff + (size_t)(c0 + c) * R + r0 + r8] = *(float4*)tmp;
    }
}

// ---------------------------------------------------------------------------
// 3. bf16 MFMA GEMM, B^T input: C[M,N] = A[M,K] @ BT[N,K]^T + bias
// ---------------------------------------------------------------------------
#define ASTR 40

template <bool BF16OUT>
__global__ __launch_bounds__(256) void gemm_bt(const short* __restrict__ A,
                                               const short* __restrict__ BT,
                                               const float* __restrict__ bias,
                                               void* __restrict__ Cout,
                                               int M, int N, int K) {
    __shared__ short As[128 * ASTR];
    __shared__ short Bs[128 * ASTR];
    int tid = threadIdx.x;
    int wave = tid >> 6, lane = tid & 63;
    int quad = lane >> 4, l15 = lane & 15;
    int m0 = blockIdx.x * 128, n0 = blockIdx.y * 128;
    int wr = (wave >> 1) * 64, wc = (wave & 1) * 64;

    f32x4 acc[4][4] = {};
    for (int k0 = 0; k0 < K; k0 += 32) {
        __syncthreads();
#pragma unroll
        for (int p = 0; p < 2; ++p) {
            int idx = tid + p * 256;
            int r = idx >> 2, c8 = (idx & 3) * 8;
            *(float4*)&As[r * ASTR + c8] = *(const float4*)&A[(size_t)(m0 + r) * K + k0 + c8];
            *(float4*)&Bs[r * ASTR + c8] = *(const float4*)&BT[(size_t)(n0 + r) * K + k0 + c8];
        }
        __syncthreads();
        bf16x8 af[4], bfr[4];
#pragma unroll
        for (int i = 0; i < 4; ++i) {
            af[i]  = *(const bf16x8*)&As[(wr + i * 16 + l15) * ASTR + quad * 8];
            bfr[i] = *(const bf16x8*)&Bs[(wc + i * 16 + l15) * ASTR + quad * 8];
        }
#pragma unroll
        for (int i = 0; i < 4; ++i)
#pragma unroll
            for (int j = 0; j < 4; ++j)
                acc[i][j] = mfma16(af[i], bfr[j], acc[i][j]);
    }
#pragma unroll
    for (int i = 0; i < 4; ++i)
#pragma unroll
        for (int j = 0; j < 4; ++j)
#pragma unroll
            for (int r = 0; r < 4; ++r) {
                int row = m0 + wr + i * 16 + quad * 4 + r;
                int col = n0 + wc + j * 16 + l15;
                float v = acc[i][j][r] + bias[col];
                if (BF16OUT) ((short*)Cout)[(size_t)row * N + col] = f2bf(v);
                else        ((float*)Cout)[(size_t)row * N + col] = v;
            }
}

// ---------------------------------------------------------------------------
// 4. attention with MFMA. block=(h, t-tile of 64), 4 waves
// ---------------------------------------------------------------------------
#define SQ 72

__global__ __launch_bounds__(256) void attn_mfma(const short* __restrict__ qkv,
                                                 const short* __restrict__ stateT,
                                                 const int* __restrict__ seg,
                                                 short* __restrict__ outb) {
    __shared__ short Qs[64 * SQ];
    __shared__ short Ks[64 * SQ];
    __shared__ short Vt[64 * SQ];
    __shared__ short Ss[64 * SQ];
    __shared__ int segT[64], segS[64];

    int h = blockIdx.x, tt = blockIdx.y;
    int t0 = tt * 64;
    int tid = threadIdx.x, wave = tid >> 6, lane = tid & 63;
    int quad = lane >> 4, l15 = lane & 15;
    int myt = wave * 16;

#pragma unroll
    for (int p = 0; p < 2; ++p) {
        int idx = tid + p * 256;
        int r = idx >> 3, c8 = (idx & 7) * 8;
        *(float4*)&Qs[r * SQ + c8] = *(const float4*)&qkv[(size_t)(t0 + r) * QKV_N + h * DH + c8];
        *(float4*)&Ks[r * SQ + c8] = *(const float4*)&stateT[(size_t)h * 4096 + r * 64 + c8];
    }
    if (tid < 64) segT[tid] = seg[t0 + tid];
    __syncthreads();

    bf16x8 qf[2];
    qf[0] = *(const bf16x8*)&Qs[(myt + l15) * SQ + quad * 8];
    qf[1] = *(const bf16x8*)&Qs[(myt + l15) * SQ + 32 + quad * 8];

    f32x4 acc[4] = {};
#pragma unroll
    for (int j = 0; j < 4; ++j) {
        bf16x8 b0 = *(const bf16x8*)&Ks[(j * 16 + l15) * SQ + quad * 8];
        bf16x8 b1 = *(const bf16x8*)&Ks[(j * 16 + l15) * SQ + 32 + quad * 8];
        acc[j] = mfma16(qf[0], b0, acc[j]);
        acc[j] = mfma16(qf[1], b1, acc[j]);
    }
#pragma unroll
    for (int r = 0; r < 4; ++r) {
        int t = myt + quad * 4 + r;
        if (segT[t] != 0) { acc[0][r] = 0.f; acc[1][r] = 0.f; acc[2][r] = 0.f; acc[3][r] = 0.f; }
    }
    int seg_t_first = segT[0];

    for (int st = 0; st <= tt; ++st) {
        int s0 = st * 64;
        if (seg[s0 + 63] < seg_t_first) continue;
        __syncthreads();
#pragma unroll
        for (int p = 0; p < 2; ++p) {
            int idx = tid + p * 256;
            int r = idx >> 3, c8 = (idx & 7) * 8;
            *(float4*)&Ks[r * SQ + c8] = *(const float4*)&qkv[(size_t)(s0 + r) * QKV_N + DD + h * DH + c8];
            union { float4 f; short s[8]; } uv;
            uv.f = *(const float4*)&qkv[(size_t)(s0 + r) * QKV_N + 2 * DD + h * DH + c8];
#pragma unroll
            for (int ii = 0; ii < 8; ++ii) {
                int i = (ii + lane) & 7;
                Vt[(c8 + i) * SQ + r] = uv.s[i];
            }
        }
        if (tid < 64) segS[tid] = seg[s0 + tid];
        __syncthreads();

        f32x4 sacc[4] = {};
#pragma unroll
        for (int j = 0; j < 4; ++j) {
            bf16x8 b0 = *(const bf16x8*)&Ks[(j * 16 + l15) * SQ + quad * 8];
            bf16x8 b1 = *(const bf16x8*)&Ks[(j * 16 + l15) * SQ + 32 + quad * 8];
            sacc[j] = mfma16(qf[0], b0, sacc[j]);
            sacc[j] = mfma16(qf[1], b1, sacc[j]);
        }
#pragma unroll
        for (int j = 0; j < 4; ++j)
#pragma unroll
            for (int r = 0; r < 4; ++r) {
                int t = myt + quad * 4 + r;
                int s = j * 16 + l15;
                bool ok = (segS[s] == segT[t]) && (s0 + s <= t0 + t);
                Ss[t * SQ + s] = ok ? f2bf(sacc[j][r]) : (short)0;
            }
        __syncthreads();

        bf16x8 sf0 = *(const bf16x8*)&Ss[(myt + l15) * SQ + quad * 8];
        bf16x8 sf1 = *(const bf16x8*)&Ss[(myt + l15) * SQ + 32 + quad * 8];
#pragma unroll
        for (int j = 0; j < 4; ++j) {
            bf16x8 b0 = *(const bf16x8*)&Vt[(j * 16 + l15) * SQ + quad * 8];
            bf16x8 b1 = *(const bf16x8*)&Vt[(j * 16 + l15) * SQ + 32 + quad * 8];
            acc[j] = mfma16(sf0, b0, acc[j]);
            acc[j] = mfma16(sf1, b1, acc[j]);
        }
    }

#pragma unroll
    for (int j = 0; j < 4; ++j)
#pragma unroll
        for (int r = 0; r < 4; ++r) {
            int t = t0 + myt + quad * 4 + r;
            int e = j * 16 + l15;
            outb[(size_t)t * DD + h * DH + e] = f2bf(acc[j][r]);
        }
}

// ---------------------------------------------------------------------------
// 5a. state partials: part[ct][h][d][e] = sum_{t in chunk ct, seg[t]==total} k_t[d] v_t[e]
//     grid (HH, 32), 4 waves, MFMA.
// ---------------------------------------------------------------------------
__global__ __launch_bounds__(256) void state_mfma(const short* __restrict__ qkv,
                                                  const int* __restrict__ seg,
                                                  const int* __restrict__ totalp,
                                                  float* __restrict__ part) {
    __shared__ short Kt[64 * SQ];  // K^T [d][t], masked
    __shared__ short Vt[64 * SQ];  // V^T [e][t]
    int h = blockIdx.x, ct = blockIdx.y;
    int t0 = ct * 64;
    int total = totalp[0];
    float* my = part + ((size_t)ct * HH + h) * 4096;
    int tid = threadIdx.x, wave = tid >> 6, lane = tid & 63;
    int quad = lane >> 4, l15 = lane & 15;

    if (seg[t0 + 63] < total) {  // no seg==total token in chunk -> zero partial
        float4 z = make_float4(0.f, 0.f, 0.f, 0.f);
#pragma unroll
        for (int p = 0; p < 4; ++p) *(float4*)&my[(tid + p * 256) * 4] = z;
        return;
    }

#pragma unroll
    for (int p = 0; p < 2; ++p) {
        int idx = tid + p * 256;
        int r = idx >> 3, c8 = (idx & 7) * 8;
        bool keep = (seg[t0 + r] == total);
        union { float4 f; short s[8]; } uk, uv;
        uk.f = *(const float4*)&qkv[(size_t)(t0 + r) * QKV_N + DD + h * DH + c8];
        uv.f = *(const float4*)&qkv[(size_t)(t0 + r) * QKV_N + 2 * DD + h * DH + c8];
#pragma unroll
        for (int ii = 0; ii < 8; ++ii) {
            int i = (ii + lane) & 7;  // rotate to spread banks
            Kt[(c8 + i) * SQ + r] = keep ? uk.s[i] : (short)0;
            Vt[(c8 + i) * SQ + r] = uv.s[i];
        }
    }
    __syncthreads();

    int myd = wave * 16;
    bf16x8 a0 = *(const bf16x8*)&Kt[(myd + l15) * SQ + quad * 8];
    bf16x8 a1 = *(const bf16x8*)&Kt[(myd + l15) * SQ + 32 + quad * 8];
    f32x4 acc[4] = {};
#pragma unroll
    for (int j = 0; j < 4; ++j) {
        bf16x8 b0 = *(const bf16x8*)&Vt[(j * 16 + l15) * SQ + quad * 8];
        bf16x8 b1 = *(const bf16x8*)&Vt[(j * 16 + l15) * SQ + 32 + quad * 8];
        acc[j] = mfma16(a0, b0, acc[j]);
        acc[j] = mfma16(a1, b1, acc[j]);
    }
#pragma unroll
    for (int j = 0; j < 4; ++j)
#pragma unroll
        for (int r = 0; r < 4; ++r)
            my[(myd + quad * 4 + r) * DH + j * 16 + l15] = acc[j][r];
}

// ---------------------------------------------------------------------------
// 5b. reduce partials: out[f] = (done_any ? 0 : state[f]) + sum_ct part[ct][f]
// ---------------------------------------------------------------------------
__global__ __launch_bounds__(256) void state_reduce(const float* __restrict__ part,
                                                    const float* __restrict__ state,
                                                    const int* __restrict__ totalp,
                                                    float* __restrict__ out) {
    int f = (blockIdx.x * 256 + threadIdx.x) * 4;  // 65536 floats / 4
    bool done_any = totalp[0] > 0;
    float4 acc = done_any ? make_float4(0.f, 0.f, 0.f, 0.f) : *(const float4*)&state[f];
#pragma unroll 8
    for (int ct = 0; ct < 32; ++ct) {
        float4 p = *(const float4*)&part[(size_t)ct * (HH * 4096) + f];
        acc.x += p.x; acc.y += p.y; acc.z += p.z; acc.w += p.w;
    }
    *(float4*)&out[f] = acc;
}

// ---------------------------------------------------------------------------
// Host launcher
// ---------------------------------------------------------------------------
extern "C" void kernel_launch(void* const* d_in, const int* in_sizes, int n_in,
                              void* d_out, int out_size, void* d_ws, size_t ws_size,
                              hipStream_t stream) {
    const float* state = (const float*)d_in[0];
    const float* x     = (const float*)d_in[1];
    const int*   done  = (const int*)d_in[2];
    const float* w_qkv = (const float*)d_in[3];
    const float* b_qkv = (const float*)d_in[4];
    const float* w_out = (const float*)d_in[5];
    const float* b_out = (const float*)d_in[6];

    char* ws = (char*)d_ws;
    int*   seg    = (int*)ws;                                  // 8 KB
    int*   totalp = (int*)(ws + 8192);
    short* x_bf   = (short*)(ws + 8448);                       // 4 MB
    short* wqT    = (short*)(ws + 8448 + 4194304);             // 6 MB
    short* woT    = (short*)(ws + 8448 + 10485760);            // 2 MB
    short* stT    = (short*)(ws + 8448 + 12582912);            // 128 KB
    short* qkvb   = (short*)(ws + 8448 + 12713984);            // 12 MB
    short* outb   = (short*)(ws + 8448 + 25296896);            // 4 MB
    // state partials alias x_bf+wqT (dead after QKV gemm): 32*16*4096 fp32 = 8 MB
    float* spart  = (float*)(ws + 8448);

    float* new_state_out = (float*)d_out;
    float* x_out         = (float*)d_out + HH * DH * DH;

    scan_kernel<<<1, 256, 0, stream>>>(done, seg, totalp);
    cast_bf16<<<(TT * DD) / (8 * 256), 256, 0, stream>>>(x, x_bf, TT * DD);
    transpose_cast<<<dim3(DD / 64, QKV_N / 64, 1), 256, 0, stream>>>(w_qkv, wqT, DD, QKV_N);
    transpose_cast<<<dim3(DD / 64, DD / 64, 1), 256, 0, stream>>>(w_out, woT, DD, DD);
    transpose_cast<<<dim3(1, 1, HH), 256, 0, stream>>>(state, stT, DH, DH);

    gemm_bt<true><<<dim3(TT / 128, QKV_N / 128), 256, 0, stream>>>(
        x_bf, wqT, b_qkv, qkvb, TT, QKV_N, DD);

    attn_mfma<<<dim3(HH, TT / 64), 256, 0, stream>>>(qkvb, stT, seg, outb);

    state_mfma<<<dim3(HH, TT / 64), 256, 0, stream>>>(qkvb, seg, totalp, spart);
    state_reduce<<<64, 256, 0, stream>>>(spart, state, totalp, new_state_out);

    gemm_bt<false><<<dim3(TT / 128, DD / 128), 256, 0, stream>>>(
        outb, woT, b_out, x_out, TT, DD, DD);
}